// Round 8
// baseline (2150.610 us; speedup 1.0000x reference)
//
#include <hip/hip_runtime.h>
#include <math.h>

// Problem constants (from setup_inputs)
#define BL 192      // b*l = 16*12
#define NREAL 325   // real sequence length
#define NPAD 352    // padded length (multiple of 2*bucket_size=32)
#define DM 256      // d_feat
#define DPOS 64     // d_pos
#define DIN 320     // d_feat + d_pos
#define NHEADS 8
#define EDIM 32     // DM / NHEADS
#define NHASH 4
#define BS 16       // bucket_size
#define NBUCK 22    // NPAD / BS
#define NCHUNK 88   // NHASH * NBUCK
#define BHTOT 1536  // BL * NHEADS
#define RROT 11     // n_buckets // 2
#define W2COLS 352  // NHEADS * NHASH * RROT
#define RTM 8       // row tile for qkv_rot_bucket kernel
#define HTM 16      // row tile for h kernel / outproj

// ---------------------------------------------------------------------------
// h = [x,ste]@w_proj + b_proj, serial-k fp32 FMA ascending (bit-exact vs the
// np reference chain).  A-operand addresses are block-uniform -> scalar loads;
// B loads are lane-coalesced; no LDS.  Pad rows (n >= NREAL) exactly 0.
__global__ __launch_bounds__(256) void h_kernel(
    const float* __restrict__ x, const float* __restrict__ ste,
    const float* __restrict__ wproj, const float* __restrict__ bproj,
    float* __restrict__ h) {
  int tile = blockIdx.x, bl = blockIdx.y;  // tile in [0, NPAD/HTM)
  int d = threadIdx.x;
  int n0 = tile * HTM;
  float acc[HTM];
#pragma unroll
  for (int m = 0; m < HTM; ++m) acc[m] = 0.f;
  if (n0 + HTM <= NREAL) {
    // fast path: all HTM rows valid
    const float* xb = x + (size_t)(bl * NREAL + n0) * DM;
    const float* sb = ste + (size_t)(bl * NREAL + n0) * DPOS;
    for (int k = 0; k < DM; k += 4) {
      float b0 = wproj[(k + 0) * DM + d];
      float b1 = wproj[(k + 1) * DM + d];
      float b2 = wproj[(k + 2) * DM + d];
      float b3 = wproj[(k + 3) * DM + d];
#pragma unroll
      for (int m = 0; m < HTM; ++m) {
        const float* xr = xb + (size_t)m * DM + k;
        acc[m] = fmaf(xr[0], b0, acc[m]);
        acc[m] = fmaf(xr[1], b1, acc[m]);
        acc[m] = fmaf(xr[2], b2, acc[m]);
        acc[m] = fmaf(xr[3], b3, acc[m]);
      }
    }
    for (int k = 0; k < DPOS; k += 4) {
      float b0 = wproj[(DM + k + 0) * DM + d];
      float b1 = wproj[(DM + k + 1) * DM + d];
      float b2 = wproj[(DM + k + 2) * DM + d];
      float b3 = wproj[(DM + k + 3) * DM + d];
#pragma unroll
      for (int m = 0; m < HTM; ++m) {
        const float* sr = sb + (size_t)m * DPOS + k;
        acc[m] = fmaf(sr[0], b0, acc[m]);
        acc[m] = fmaf(sr[1], b1, acc[m]);
        acc[m] = fmaf(sr[2], b2, acc[m]);
        acc[m] = fmaf(sr[3], b3, acc[m]);
      }
    }
  } else if (n0 < NREAL) {
    // partial tile (rows n0..NREAL-1 valid) — rare (192 blocks total)
#pragma unroll
    for (int m = 0; m < HTM; ++m) {
      if (n0 + m < NREAL) {
        const float* xr = x + (size_t)(bl * NREAL + n0 + m) * DM;
        const float* sr = ste + (size_t)(bl * NREAL + n0 + m) * DPOS;
        for (int k = 0; k < DM; ++k) acc[m] = fmaf(xr[k], wproj[k * DM + d], acc[m]);
        for (int k = 0; k < DPOS; ++k)
          acc[m] = fmaf(sr[k], wproj[(DM + k) * DM + d], acc[m]);
      }
    }
  }
  float bb = bproj[d];
#pragma unroll
  for (int m = 0; m < HTM; ++m) {
    int n = n0 + m;
    h[((size_t)(bl * NPAD + n)) * DM + d] = (n < NREAL) ? (acc[m] + bb) : 0.f;
  }
}

// ---------------------------------------------------------------------------
// qk = h@w_qk, v = h@w_v (serial-k fp32 FMA ascending, bit-exact), then
//   rot = einsum(qk, rotations)   fp32, separate mul+add (no fma)
//   bucket = argmax(concat(rot,-rot)), first-max tie rule.
__global__ __launch_bounds__(256) void qkv_rot_bucket_kernel(
    const float* __restrict__ h, const float* __restrict__ wqk,
    const float* __restrict__ wv, const float* __restrict__ rotations,
    int* __restrict__ buckets, float* __restrict__ qk_out,
    float* __restrict__ v_out) {
  int tile = blockIdx.x, bl = blockIdx.y;  // tile in [0,44)
  int tid = threadIdx.x;
  __shared__ float Qs[RTM][DM];     //  8,192 B
  __shared__ float Rs[RTM][W2COLS]; // 11,264 B
  int n0 = tile * RTM;
  const float* hb = h + (size_t)(bl * NPAD + n0) * DM;
  float aq[RTM], av[RTM];
#pragma unroll
  for (int m = 0; m < RTM; ++m) { aq[m] = 0.f; av[m] = 0.f; }
  for (int k = 0; k < DM; k += 4) {
    float q0 = wqk[(k + 0) * DM + tid];
    float q1 = wqk[(k + 1) * DM + tid];
    float q2 = wqk[(k + 2) * DM + tid];
    float q3 = wqk[(k + 3) * DM + tid];
    float w0 = wv[(k + 0) * DM + tid];
    float w1 = wv[(k + 1) * DM + tid];
    float w2 = wv[(k + 2) * DM + tid];
    float w3 = wv[(k + 3) * DM + tid];
#pragma unroll
    for (int m = 0; m < RTM; ++m) {
      const float* hr = hb + (size_t)m * DM + k;
      float a0 = hr[0], a1 = hr[1], a2 = hr[2], a3 = hr[3];
      aq[m] = fmaf(a0, q0, aq[m]);
      aq[m] = fmaf(a1, q1, aq[m]);
      aq[m] = fmaf(a2, q2, aq[m]);
      aq[m] = fmaf(a3, q3, aq[m]);
      av[m] = fmaf(a0, w0, av[m]);
      av[m] = fmaf(a1, w1, av[m]);
      av[m] = fmaf(a2, w2, av[m]);
      av[m] = fmaf(a3, w3, av[m]);
    }
  }
  {
    int head = tid >> 5, e = tid & 31;
    size_t bh = (size_t)(bl * NHEADS + head);
#pragma unroll
    for (int m = 0; m < RTM; ++m) {
      Qs[m][tid] = aq[m];
      int n = n0 + m;
      qk_out[(bh * NPAD + n) * EDIM + e] = aq[m];
      v_out[(bh * NPAD + n) * EDIM + e] = av[m];
    }
  }
  __syncthreads();
  for (int col = tid; col < W2COLS; col += 256) {
    // rot: serial-e fp32, separate mul and add (no fma)
    int head = col / 44;
    int hr = col - head * 44;
    int hs = hr / RROT;
    int r = hr - hs * RROT;
    float acc[RTM];
#pragma unroll
    for (int m = 0; m < RTM; ++m) acc[m] = 0.f;
    {
#pragma clang fp contract(off)
      for (int e = 0; e < EDIM; ++e) {
        float rr = rotations[(e * NHASH + hs) * RROT + r];
#pragma unroll
        for (int m = 0; m < RTM; ++m) {
          float p = Qs[m][head * EDIM + e] * rr;
          acc[m] = acc[m] + p;
        }
      }
    }
#pragma unroll
    for (int m = 0; m < RTM; ++m) Rs[m][col] = acc[m];
  }
  __syncthreads();
  {
    int m = tid >> 5;
    int rest = tid & 31;
    int head = rest >> 2;
    int hs = rest & 3;
    int cbase = head * 44 + hs * RROT;
    // argmax over concat([rot, -rot]), first-occurrence tie rule (strict >)
    float bestv = Rs[m][cbase];
    int best = 0;
    for (int r = 1; r < RROT; ++r) {
      float dv = Rs[m][cbase + r];
      if (dv > bestv) { bestv = dv; best = r; }
    }
    for (int r = 0; r < RROT; ++r) {
      float dv = -Rs[m][cbase + r];
      if (dv > bestv) { bestv = dv; best = RROT + r; }
    }
    int n = n0 + m;
    int bh = bl * NHEADS + head;
    buckets[((size_t)(bh * NHASH + hs)) * NPAD + n] = best;
  }
}

// ---------------------------------------------------------------------------
// Stable counting sort per (bh, hash): keys bucket*NPAD+n unique → exact argsort
__global__ __launch_bounds__(384) void sort_kernel(const int* __restrict__ buckets,
                                                   int* __restrict__ st) {
  int bh = blockIdx.x, hs = blockIdx.y;
  int n = threadIdx.x;
  __shared__ int buck[NPAD];
  const int* brow = buckets + ((size_t)(bh * NHASH + hs)) * NPAD;
  if (n < NPAD) buck[n] = brow[n];
  __syncthreads();
  if (n < NPAD) {
    int b = buck[n];
    int dest = 0;
    for (int m2 = 0; m2 < NPAD; ++m2) {
      int bm = buck[m2];
      dest += (int)((bm < b) | ((bm == b) & (m2 < n)));
    }
    st[((size_t)(bh * NHASH + hs)) * NPAD + dest] = n;
  }
}

// ---------------------------------------------------------------------------
// Fused attention v3: one block per bh, 55 KB LDS (2 blocks/CU), 16 waves/CU.
// qk in LDS unpadded [NPAD][32] with XOR bank-swizzle (f4 index ^= row&7).
// q-row access = ONE ds_read_b32 per q + 32 lane-shuffle broadcasts (cuts
// LDS-pipe instructions 72 -> 16 per chunk-iter; dot fmaf chain order
// unchanged -> bit-identical).  Phase 1: lse into LDS.  Combine L.  Phase 2:
// recompute dots (identical ops), p = exp(dot - L), PV via shuffles, global
// atomicAdd into pre-zeroed att.
__global__ __launch_bounds__(512, 4) void attn_fused_kernel(
    const float* __restrict__ qk, const float* __restrict__ v,
    const int* __restrict__ st, float* __restrict__ att) {
  int bh = blockIdx.x;
  int t = threadIdx.x;
  int w = t >> 6;       // wave 0..7
  int lane = t & 63;
  int i2 = lane >> 5;   // query-parity half
  int j = lane & 31;    // key index (dots) / output dim (PV)

  __shared__ float qk_s[NPAD * EDIM];        // 45,056 B (swizzled)
  __shared__ unsigned short stf[NHASH * NPAD];  // 2,816 B
  __shared__ float ll_s[NHASH][NPAD];        //  5,632 B
  __shared__ float rnorm_s[NPAD];            //  1,408 B
  __shared__ float L_s[NPAD];                //  1,408 B  -> 56,320 B total

  const float* qkb = qk + (size_t)bh * NPAD * EDIM;
  const float* vb = v + (size_t)bh * NPAD * EDIM;
  const int* strow = st + (size_t)bh * (NHASH * NPAD);

  // ---- stage qk (swizzled: float4 index ^= (row&7)) + st ----
  float4* qk4 = (float4*)qk_s;
  for (int idx = t; idx < NPAD * 8; idx += 512) {
    int n = idx >> 3, c4 = idx & 7;
    qk4[(n * 8 + c4) ^ (n & 7)] = ((const float4*)qkb)[idx];
  }
  for (int idx = t; idx < NHASH * NPAD; idx += 512)
    stf[idx] = (unsigned short)strow[idx];
  __syncthreads();
  // ---- rnorm: serial-e ascending fmaf (same rounding as before) ----
  for (int n = t; n < NPAD; n += 512) {
    int base = n * EDIM;
    int sw = (n & 7) << 2;
    float s = 0.f;
    for (int e = 0; e < EDIM; ++e) {
      float kv = qk_s[(base + e) ^ sw];
      s = fmaf(kv, kv, s);
    }
    rnorm_s[n] = 1.0f / fmaxf(sqrtf(s), 1e-12f);
  }
  __syncthreads();

  // ---- phase 1: per-wave chunks, lse (no barriers inside) ----
  for (int c = w; c < NCHUNK; c += 8) {
    int pc = (c + NCHUNK - 1) % NCHUNK;
    int hs = c / NBUCK;
    int kp = (j < BS) ? stf[c * BS + j] : stf[pc * BS + (j - BS)];
    float kr[EDIM];
    {
      const float4* krow4 = qk4;
      int kb = kp * 8, ks = kp & 7;
#pragma unroll
      for (int e4 = 0; e4 < 8; ++e4) {
        float4 kv = krow4[(kb + e4) ^ ks];
        kr[e4 * 4 + 0] = kv.x; kr[e4 * 4 + 1] = kv.y;
        kr[e4 * 4 + 2] = kv.z; kr[e4 * 4 + 3] = kv.w;
      }
    }
    float scale = rnorm_s[kp] * 0.17677669529663688f;  // * E^-0.5
#pragma unroll
    for (int i = 0; i < 8; ++i) {
      int q = i * 2 + i2;
      int qp = stf[c * BS + q];
      // one b32 per lane: lane j holds q[j]; broadcast via shuffles below
      float qreg = qk_s[(qp * EDIM + j) ^ ((qp & 7) << 2)];
      float dot = 0.f;
#pragma unroll
      for (int e = 0; e < EDIM; ++e) {
        float qe = __shfl(qreg, e, 32);
        dot = fmaf(qe, kr[e], dot);
      }
      dot *= scale;
      if (qp == kp) dot = -50000.0f;
      float mx = dot;
#pragma unroll
      for (int off = 16; off > 0; off >>= 1) mx = fmaxf(mx, __shfl_xor(mx, off, 32));
      float ex = expf(dot - mx);
      float sm = ex;
#pragma unroll
      for (int off = 16; off > 0; off >>= 1) sm += __shfl_xor(sm, off, 32);
      if (j == 0) ll_s[hs][qp] = mx + logf(sm);
    }
  }
  __syncthreads();
  // ---- combine L over hashes ----
  for (int n = t; n < NPAD; n += 512) {
    float l0 = ll_s[0][n], l1 = ll_s[1][n], l2 = ll_s[2][n], l3 = ll_s[3][n];
    float m = fmaxf(fmaxf(l0, l1), fmaxf(l2, l3));
    float s = expf(l0 - m) + expf(l1 - m) + expf(l2 - m) + expf(l3 - m);
    L_s[n] = m + logf(s);
  }
  __syncthreads();

  // ---- phase 2: recompute dots (identical ops), PV via shuffles ----
  int head = bh & 7, bl = bh >> 3;
  float* attb = att + ((size_t)bl * NPAD) * DM + head * EDIM;
  for (int c = w; c < NCHUNK; c += 8) {
    int pc = (c + NCHUNK - 1) % NCHUNK;
    int kp = (j < BS) ? stf[c * BS + j] : stf[pc * BS + (j - BS)];
    float kr[EDIM];
    {
      const float4* krow4 = qk4;
      int kb = kp * 8, ks = kp & 7;
#pragma unroll
      for (int e4 = 0; e4 < 8; ++e4) {
        float4 kv = krow4[(kb + e4) ^ ks];
        kr[e4 * 4 + 0] = kv.x; kr[e4 * 4 + 1] = kv.y;
        kr[e4 * 4 + 2] = kv.z; kr[e4 * 4 + 3] = kv.w;
      }
    }
    float scale = rnorm_s[kp] * 0.17677669529663688f;
    // V gather: vr[jj] = v[kp(jj)][e=j]; coalesced 128B row reads (L2-hot)
    float vr[32];
#pragma unroll
    for (int jj = 0; jj < 32; ++jj) {
      int kpj = (jj < BS) ? stf[c * BS + jj] : stf[pc * BS + (jj - BS)];
      vr[jj] = vb[kpj * EDIM + j];
    }
#pragma unroll
    for (int i = 0; i < 8; ++i) {
      int q = i * 2 + i2;
      int qp = stf[c * BS + q];
      float qreg = qk_s[(qp * EDIM + j) ^ ((qp & 7) << 2)];
      float dot = 0.f;
#pragma unroll
      for (int e = 0; e < EDIM; ++e) {
        float qe = __shfl(qreg, e, 32);
        dot = fmaf(qe, kr[e], dot);
      }
      dot *= scale;
      if (qp == kp) dot = -50000.0f;
      float p = expf(dot - L_s[qp]);
      // PV: redistribute p across the 32-lane segment; jj ascending fmaf
      float acc = 0.f;
#pragma unroll
      for (int jj = 0; jj < 32; ++jj) {
        float pb = __shfl(p, jj, 32);
        acc = fmaf(pb, vr[jj], acc);
      }
      atomicAdd(&attb[(size_t)qp * DM + j], acc);
    }
  }
}

// ---------------------------------------------------------------------------
// out = att @ w_out + b_out (fp32 serial-k, scalar A loads), real rows only
__global__ __launch_bounds__(256) void outproj_kernel(
    const float* __restrict__ att, const float* __restrict__ w,
    const float* __restrict__ bias, float* __restrict__ out) {
  int tile = blockIdx.x, bl = blockIdx.y;
  int d = threadIdx.x;
  int n0 = tile * HTM;
  float acc[HTM];
#pragma unroll
  for (int m = 0; m < HTM; ++m) acc[m] = 0.f;
  if (n0 + HTM <= NREAL) {
    const float* ab = att + (size_t)(bl * NPAD + n0) * DM;
    for (int k = 0; k < DM; k += 4) {
      float b0 = w[(k + 0) * DM + d];
      float b1 = w[(k + 1) * DM + d];
      float b2 = w[(k + 2) * DM + d];
      float b3 = w[(k + 3) * DM + d];
#pragma unroll
      for (int m = 0; m < HTM; ++m) {
        const float* ar = ab + (size_t)m * DM + k;
        acc[m] = fmaf(ar[0], b0, acc[m]);
        acc[m] = fmaf(ar[1], b1, acc[m]);
        acc[m] = fmaf(ar[2], b2, acc[m]);
        acc[m] = fmaf(ar[3], b3, acc[m]);
      }
    }
  } else if (n0 < NREAL) {
#pragma unroll
    for (int m = 0; m < HTM; ++m) {
      if (n0 + m < NREAL) {
        const float* ar = att + (size_t)(bl * NPAD + n0 + m) * DM;
        for (int k = 0; k < DM; ++k) acc[m] = fmaf(ar[k], w[k * DM + d], acc[m]);
      }
    }
  } else {
    return;
  }
  float bb = bias[d];
#pragma unroll
  for (int m = 0; m < HTM; ++m) {
    int n = n0 + m;
    if (n < NREAL) out[((size_t)(bl * NREAL + n)) * DM + d] = acc[m] + bb;
  }
}

// ---------------------------------------------------------------------------
extern "C" void kernel_launch(void* const* d_in, const int* in_sizes, int n_in,
                              void* d_out, int out_size, void* d_ws, size_t ws_size,
                              hipStream_t stream) {
  (void)in_sizes; (void)n_in; (void)out_size;
  const float* x = (const float*)d_in[0];
  const float* ste = (const float*)d_in[1];
  const float* w_proj = (const float*)d_in[2];
  const float* b_proj = (const float*)d_in[3];
  const float* w_qk = (const float*)d_in[4];
  const float* w_v = (const float*)d_in[5];
  const float* w_out = (const float*)d_in[6];
  const float* b_out = (const float*)d_in[7];
  const float* rotations = (const float*)d_in[8];
  float* out = (float*)d_out;

  // Workspace layout (~216 MB):
  const size_t szh = (size_t)BL * NPAD * DM;         // 17,301,504 elements
  const size_t szst = (size_t)BHTOT * NHASH * NPAD;  // 2,162,688 elements
  const size_t needed = 3 * szh * 4 + 2 * szst * 4;
  if (ws_size < needed) return;  // diagnosable clean failure, not a fault

  float* qk = (float*)d_ws;
  float* v = qk + szh;
  float* att = v + szh;  // also the h buffer (h consumed before att written)
  float* h = att;
  int* st = (int*)(att + szh);
  int* buckets = st + szst;

  h_kernel<<<dim3(NPAD / HTM, BL), dim3(256), 0, stream>>>(
      x, ste, w_proj, b_proj, h);
  qkv_rot_bucket_kernel<<<dim3(NPAD / RTM, BL), dim3(256), 0, stream>>>(
      h, w_qk, w_v, rotations, buckets, qk, v);
  // att aliases h; h fully consumed above — zero it for the atomic accumulate.
  (void)hipMemsetAsync(att, 0, szh * sizeof(float), stream);
  sort_kernel<<<dim3(BHTOT, NHASH), dim3(384), 0, stream>>>(buckets, st);
  attn_fused_kernel<<<dim3(BHTOT), dim3(512), 0, stream>>>(qk, v, st, att);
  outproj_kernel<<<dim3(21, BL), dim3(256), 0, stream>>>(att, w_out, b_out, out);
}

// Round 9
// 1460.917 us; speedup vs baseline: 1.4721x; 1.4721x over previous
//
#include <hip/hip_runtime.h>
#include <math.h>

// Problem constants (from setup_inputs)
#define BL 192      // b*l = 16*12
#define NREAL 325   // real sequence length
#define NPAD 352    // padded length (multiple of 2*bucket_size=32)
#define DM 256      // d_feat
#define DPOS 64     // d_pos
#define DIN 320     // d_feat + d_pos
#define NHEADS 8
#define EDIM 32     // DM / NHEADS
#define NHASH 4
#define BS 16       // bucket_size
#define NBUCK 22    // NPAD / BS
#define NCHUNK 88   // NHASH * NBUCK
#define BHTOT 1536  // BL * NHEADS
#define RROT 11     // n_buckets // 2
#define W2COLS 352  // NHEADS * NHASH * RROT
#define RTM 8       // row tile for qkv_rot_bucket kernel
#define HTM 16      // row tile for h kernel / outproj
#define QKP 9       // float4s per padded qk row (36 floats; 144 B, 16B-aligned)
#define CITER 11    // chunk iterations per wave (NCHUNK / 8 waves)

// ---------------------------------------------------------------------------
// h = [x,ste]@w_proj + b_proj, serial-k fp32 FMA ascending (bit-exact vs the
// np reference chain).  A-operand addresses are block-uniform -> scalar loads;
// B loads are lane-coalesced; no LDS.  Pad rows (n >= NREAL) exactly 0.
__global__ __launch_bounds__(256) void h_kernel(
    const float* __restrict__ x, const float* __restrict__ ste,
    const float* __restrict__ wproj, const float* __restrict__ bproj,
    float* __restrict__ h) {
  int tile = blockIdx.x, bl = blockIdx.y;  // tile in [0, NPAD/HTM)
  int d = threadIdx.x;
  int n0 = tile * HTM;
  float acc[HTM];
#pragma unroll
  for (int m = 0; m < HTM; ++m) acc[m] = 0.f;
  if (n0 + HTM <= NREAL) {
    // fast path: all HTM rows valid
    const float* xb = x + (size_t)(bl * NREAL + n0) * DM;
    const float* sb = ste + (size_t)(bl * NREAL + n0) * DPOS;
    for (int k = 0; k < DM; k += 4) {
      float b0 = wproj[(k + 0) * DM + d];
      float b1 = wproj[(k + 1) * DM + d];
      float b2 = wproj[(k + 2) * DM + d];
      float b3 = wproj[(k + 3) * DM + d];
#pragma unroll
      for (int m = 0; m < HTM; ++m) {
        const float* xr = xb + (size_t)m * DM + k;
        acc[m] = fmaf(xr[0], b0, acc[m]);
        acc[m] = fmaf(xr[1], b1, acc[m]);
        acc[m] = fmaf(xr[2], b2, acc[m]);
        acc[m] = fmaf(xr[3], b3, acc[m]);
      }
    }
    for (int k = 0; k < DPOS; k += 4) {
      float b0 = wproj[(DM + k + 0) * DM + d];
      float b1 = wproj[(DM + k + 1) * DM + d];
      float b2 = wproj[(DM + k + 2) * DM + d];
      float b3 = wproj[(DM + k + 3) * DM + d];
#pragma unroll
      for (int m = 0; m < HTM; ++m) {
        const float* sr = sb + (size_t)m * DPOS + k;
        acc[m] = fmaf(sr[0], b0, acc[m]);
        acc[m] = fmaf(sr[1], b1, acc[m]);
        acc[m] = fmaf(sr[2], b2, acc[m]);
        acc[m] = fmaf(sr[3], b3, acc[m]);
      }
    }
  } else if (n0 < NREAL) {
    // partial tile (rows n0..NREAL-1 valid) — rare (192 blocks total)
#pragma unroll
    for (int m = 0; m < HTM; ++m) {
      if (n0 + m < NREAL) {
        const float* xr = x + (size_t)(bl * NREAL + n0 + m) * DM;
        const float* sr = ste + (size_t)(bl * NREAL + n0 + m) * DPOS;
        for (int k = 0; k < DM; ++k) acc[m] = fmaf(xr[k], wproj[k * DM + d], acc[m]);
        for (int k = 0; k < DPOS; ++k)
          acc[m] = fmaf(sr[k], wproj[(DM + k) * DM + d], acc[m]);
      }
    }
  }
  float bb = bproj[d];
#pragma unroll
  for (int m = 0; m < HTM; ++m) {
    int n = n0 + m;
    h[((size_t)(bl * NPAD + n)) * DM + d] = (n < NREAL) ? (acc[m] + bb) : 0.f;
  }
}

// ---------------------------------------------------------------------------
// qk = h@w_qk, v = h@w_v (serial-k fp32 FMA ascending, bit-exact), then
//   rot = einsum(qk, rotations)   fp32, separate mul+add (no fma)
//   bucket = argmax(concat(rot,-rot)), first-max tie rule.
__global__ __launch_bounds__(256) void qkv_rot_bucket_kernel(
    const float* __restrict__ h, const float* __restrict__ wqk,
    const float* __restrict__ wv, const float* __restrict__ rotations,
    int* __restrict__ buckets, float* __restrict__ qk_out,
    float* __restrict__ v_out) {
  int tile = blockIdx.x, bl = blockIdx.y;  // tile in [0,44)
  int tid = threadIdx.x;
  __shared__ float Qs[RTM][DM];     //  8,192 B
  __shared__ float Rs[RTM][W2COLS]; // 11,264 B
  int n0 = tile * RTM;
  const float* hb = h + (size_t)(bl * NPAD + n0) * DM;
  float aq[RTM], av[RTM];
#pragma unroll
  for (int m = 0; m < RTM; ++m) { aq[m] = 0.f; av[m] = 0.f; }
  for (int k = 0; k < DM; k += 4) {
    float q0 = wqk[(k + 0) * DM + tid];
    float q1 = wqk[(k + 1) * DM + tid];
    float q2 = wqk[(k + 2) * DM + tid];
    float q3 = wqk[(k + 3) * DM + tid];
    float w0 = wv[(k + 0) * DM + tid];
    float w1 = wv[(k + 1) * DM + tid];
    float w2 = wv[(k + 2) * DM + tid];
    float w3 = wv[(k + 3) * DM + tid];
#pragma unroll
    for (int m = 0; m < RTM; ++m) {
      const float* hr = hb + (size_t)m * DM + k;
      float a0 = hr[0], a1 = hr[1], a2 = hr[2], a3 = hr[3];
      aq[m] = fmaf(a0, q0, aq[m]);
      aq[m] = fmaf(a1, q1, aq[m]);
      aq[m] = fmaf(a2, q2, aq[m]);
      aq[m] = fmaf(a3, q3, aq[m]);
      av[m] = fmaf(a0, w0, av[m]);
      av[m] = fmaf(a1, w1, av[m]);
      av[m] = fmaf(a2, w2, av[m]);
      av[m] = fmaf(a3, w3, av[m]);
    }
  }
  {
    int head = tid >> 5, e = tid & 31;
    size_t bh = (size_t)(bl * NHEADS + head);
#pragma unroll
    for (int m = 0; m < RTM; ++m) {
      Qs[m][tid] = aq[m];
      int n = n0 + m;
      qk_out[(bh * NPAD + n) * EDIM + e] = aq[m];
      v_out[(bh * NPAD + n) * EDIM + e] = av[m];
    }
  }
  __syncthreads();
  for (int col = tid; col < W2COLS; col += 256) {
    // rot: serial-e fp32, separate mul and add (no fma)
    int head = col / 44;
    int hr = col - head * 44;
    int hs = hr / RROT;
    int r = hr - hs * RROT;
    float acc[RTM];
#pragma unroll
    for (int m = 0; m < RTM; ++m) acc[m] = 0.f;
    {
#pragma clang fp contract(off)
      for (int e = 0; e < EDIM; ++e) {
        float rr = rotations[(e * NHASH + hs) * RROT + r];
#pragma unroll
        for (int m = 0; m < RTM; ++m) {
          float p = Qs[m][head * EDIM + e] * rr;
          acc[m] = acc[m] + p;
        }
      }
    }
#pragma unroll
    for (int m = 0; m < RTM; ++m) Rs[m][col] = acc[m];
  }
  __syncthreads();
  {
    int m = tid >> 5;
    int rest = tid & 31;
    int head = rest >> 2;
    int hs = rest & 3;
    int cbase = head * 44 + hs * RROT;
    // argmax over concat([rot, -rot]), first-occurrence tie rule (strict >)
    float bestv = Rs[m][cbase];
    int best = 0;
    for (int r = 1; r < RROT; ++r) {
      float dv = Rs[m][cbase + r];
      if (dv > bestv) { bestv = dv; best = r; }
    }
    for (int r = 0; r < RROT; ++r) {
      float dv = -Rs[m][cbase + r];
      if (dv > bestv) { bestv = dv; best = RROT + r; }
    }
    int n = n0 + m;
    int bh = bl * NHEADS + head;
    buckets[((size_t)(bh * NHASH + hs)) * NPAD + n] = best;
  }
}

// ---------------------------------------------------------------------------
// Stable counting sort per (bh, hash): keys bucket*NPAD+n unique → exact argsort
__global__ __launch_bounds__(384) void sort_kernel(const int* __restrict__ buckets,
                                                   int* __restrict__ st) {
  int bh = blockIdx.x, hs = blockIdx.y;
  int n = threadIdx.x;
  __shared__ int buck[NPAD];
  const int* brow = buckets + ((size_t)(bh * NHASH + hs)) * NPAD;
  if (n < NPAD) buck[n] = brow[n];
  __syncthreads();
  if (n < NPAD) {
    int b = buck[n];
    int dest = 0;
    for (int m2 = 0; m2 < NPAD; ++m2) {
      int bm = buck[m2];
      dest += (int)((bm < b) | ((bm == b) & (m2 < n)));
    }
    st[((size_t)(bh * NHASH + hs)) * NPAD + dest] = n;
  }
}

// ---------------------------------------------------------------------------
// Fused attention v4 (R7 structure + dot-save + LDS-tile PV).
// One block per bh, 8 waves.  DS-pipe is the bottleneck (R8 lesson: __shfl is
// ds_bpermute, an LDS-pipe op).  v4 cuts DS ops:
//   - phase 1 computes dots ONCE, saves them in registers (dsave[11][8],
//     fully unrolled -> static indices, no scratch); phase 2 does NO k-row
//     gathers (the bank-conflict source) and NO q-row reads.
//   - PV transposes p through a per-wave LDS tile (1 b32 write + 8 b128
//     broadcast reads per q) instead of 32 ds_bpermute per q.
// All fp32 op orders identical to R7 -> bit-identical output.
__global__ __launch_bounds__(512) void attn_fused_kernel(
    const float* __restrict__ qk, const float* __restrict__ v,
    const int* __restrict__ st, float* __restrict__ att) {
  int bh = blockIdx.x;
  int t = threadIdx.x;
  int w = t >> 6;       // wave 0..7
  int lane = t & 63;
  int i2 = lane >> 5;   // query-parity half
  int j = lane & 31;    // key index (dots) / output dim (PV)

  __shared__ float4 qk4[NPAD][QKP];     // 50,688 B (rows padded to 36 floats)
  __shared__ int stf[NHASH * NPAD];     //  5,632 B
  __shared__ float ll_s[NHASH][NPAD];   //  5,632 B
  __shared__ float rnorm_s[NPAD];       //  1,408 B
  __shared__ float L_s[NPAD];           //  1,408 B
  __shared__ float psw_all[8][16 * 36]; // 18,432 B  -> 83,200 B total

  const float* qk_s = (const float*)qk4;
  const float* qkb = qk + (size_t)bh * NPAD * EDIM;
  const float* vb = v + (size_t)bh * NPAD * EDIM;
  const int* strow = st + (size_t)bh * (NHASH * NPAD);

  float dsave[CITER][8];  // per-lane masked dots, phase1 -> phase2

  // ---- stage qk (padded rows) + st ----
  for (int idx = t; idx < NPAD * 8; idx += 512) {
    int n = idx >> 3, c4 = idx & 7;
    qk4[n][c4] = ((const float4*)qkb)[idx];
  }
  for (int idx = t; idx < NHASH * NPAD; idx += 512) stf[idx] = strow[idx];
  __syncthreads();
  // ---- rnorm: serial-e ascending fmaf (same rounding as before) ----
  for (int n = t; n < NPAD; n += 512) {
    const float* row = (const float*)qk4[n];
    float s = 0.f;
    for (int e = 0; e < EDIM; ++e) s = fmaf(row[e], row[e], s);
    rnorm_s[n] = 1.0f / fmaxf(sqrtf(s), 1e-12f);
  }
  __syncthreads();

  // ---- phase 1: per-wave chunks, dots (saved) + lse ----
#pragma unroll
  for (int ci = 0; ci < CITER; ++ci) {
    int c = w + ci * 8;
    int pc = (c + NCHUNK - 1) % NCHUNK;
    int hs = c / NBUCK;
    int kp = (j < BS) ? stf[c * BS + j] : stf[pc * BS + (j - BS)];
    float kr[EDIM];
    {
      const float4* krow = qk4[kp];
#pragma unroll
      for (int e4 = 0; e4 < 8; ++e4) {
        float4 kv = krow[e4];
        kr[e4 * 4 + 0] = kv.x; kr[e4 * 4 + 1] = kv.y;
        kr[e4 * 4 + 2] = kv.z; kr[e4 * 4 + 3] = kv.w;
      }
    }
    float scale = rnorm_s[kp] * 0.17677669529663688f;  // * E^-0.5
#pragma unroll
    for (int i = 0; i < 8; ++i) {
      int q = i * 2 + i2;
      int qp = stf[c * BS + q];
      const float4* qrow = qk4[qp];
      float dot = 0.f;
#pragma unroll
      for (int e4 = 0; e4 < 8; ++e4) {
        float4 qv = qrow[e4];
        dot = fmaf(qv.x, kr[e4 * 4 + 0], dot);
        dot = fmaf(qv.y, kr[e4 * 4 + 1], dot);
        dot = fmaf(qv.z, kr[e4 * 4 + 2], dot);
        dot = fmaf(qv.w, kr[e4 * 4 + 3], dot);
      }
      dot *= scale;
      if (qp == kp) dot = -50000.0f;
      dsave[ci][i] = dot;  // reuse in phase 2 (bit-identical to recompute)
      float mx = dot;
#pragma unroll
      for (int off = 16; off > 0; off >>= 1) mx = fmaxf(mx, __shfl_xor(mx, off, 32));
      float ex = expf(dot - mx);
      float sm = ex;
#pragma unroll
      for (int off = 16; off > 0; off >>= 1) sm += __shfl_xor(sm, off, 32);
      if (j == 0) ll_s[hs][qp] = mx + logf(sm);
    }
  }
  __syncthreads();
  // ---- combine L over hashes ----
  for (int n = t; n < NPAD; n += 512) {
    float l0 = ll_s[0][n], l1 = ll_s[1][n], l2 = ll_s[2][n], l3 = ll_s[3][n];
    float m = fmaxf(fmaxf(l0, l1), fmaxf(l2, l3));
    float s = expf(l0 - m) + expf(l1 - m) + expf(l2 - m) + expf(l3 - m);
    L_s[n] = m + logf(s);
  }
  __syncthreads();

  // ---- phase 2: p = exp(dsave - L), PV via per-wave LDS tile ----
  int head = bh & 7, bl = bh >> 3;
  float* attb = att + ((size_t)bl * NPAD) * DM + head * EDIM;
  float* psw = psw_all[w];
#pragma unroll
  for (int ci = 0; ci < CITER; ++ci) {
    int c = w + ci * 8;
    int pc = (c + NCHUNK - 1) % NCHUNK;
    // V gather: vr[jj] = v[kp(jj)][e=j]; coalesced 128B row reads (L2-hot)
    float vr[32];
#pragma unroll
    for (int jj = 0; jj < 32; ++jj) {
      int kpj = (jj < BS) ? stf[c * BS + jj] : stf[pc * BS + (jj - BS)];
      vr[jj] = vb[kpj * EDIM + j];
    }
    // write p tiles (lane (i2,j) writes row q = i*2+i2, word j; bank-clean)
#pragma unroll
    for (int i = 0; i < 8; ++i) {
      int q = i * 2 + i2;
      int qp = stf[c * BS + q];
      psw[q * 36 + j] = expf(dsave[ci][i] - L_s[qp]);
    }
    // read back (broadcast b128 per segment) and accumulate PV
#pragma unroll
    for (int i = 0; i < 8; ++i) {
      int q = i * 2 + i2;
      int qp = stf[c * BS + q];
      const float4* prow = (const float4*)(psw + q * 36);
      float acc = 0.f;
#pragma unroll
      for (int j4 = 0; j4 < 8; ++j4) {
        float4 pv = prow[j4];
        acc = fmaf(pv.x, vr[j4 * 4 + 0], acc);
        acc = fmaf(pv.y, vr[j4 * 4 + 1], acc);
        acc = fmaf(pv.z, vr[j4 * 4 + 2], acc);
        acc = fmaf(pv.w, vr[j4 * 4 + 3], acc);
      }
      atomicAdd(&attb[(size_t)qp * DM + j], acc);
    }
  }
}

// ---------------------------------------------------------------------------
// out = att @ w_out + b_out (fp32 serial-k, scalar A loads), real rows only
__global__ __launch_bounds__(256) void outproj_kernel(
    const float* __restrict__ att, const float* __restrict__ w,
    const float* __restrict__ bias, float* __restrict__ out) {
  int tile = blockIdx.x, bl = blockIdx.y;
  int d = threadIdx.x;
  int n0 = tile * HTM;
  float acc[HTM];
#pragma unroll
  for (int m = 0; m < HTM; ++m) acc[m] = 0.f;
  if (n0 + HTM <= NREAL) {
    const float* ab = att + (size_t)(bl * NPAD + n0) * DM;
    for (int k = 0; k < DM; k += 4) {
      float b0 = w[(k + 0) * DM + d];
      float b1 = w[(k + 1) * DM + d];
      float b2 = w[(k + 2) * DM + d];
      float b3 = w[(k + 3) * DM + d];
#pragma unroll
      for (int m = 0; m < HTM; ++m) {
        const float* ar = ab + (size_t)m * DM + k;
        acc[m] = fmaf(ar[0], b0, acc[m]);
        acc[m] = fmaf(ar[1], b1, acc[m]);
        acc[m] = fmaf(ar[2], b2, acc[m]);
        acc[m] = fmaf(ar[3], b3, acc[m]);
      }
    }
  } else if (n0 < NREAL) {
#pragma unroll
    for (int m = 0; m < HTM; ++m) {
      if (n0 + m < NREAL) {
        const float* ar = att + (size_t)(bl * NPAD + n0 + m) * DM;
        for (int k = 0; k < DM; ++k) acc[m] = fmaf(ar[k], w[k * DM + d], acc[m]);
      }
    }
  } else {
    return;
  }
  float bb = bias[d];
#pragma unroll
  for (int m = 0; m < HTM; ++m) {
    int n = n0 + m;
    if (n < NREAL) out[((size_t)(bl * NREAL + n)) * DM + d] = acc[m] + bb;
  }
}

// ---------------------------------------------------------------------------
extern "C" void kernel_launch(void* const* d_in, const int* in_sizes, int n_in,
                              void* d_out, int out_size, void* d_ws, size_t ws_size,
                              hipStream_t stream) {
  (void)in_sizes; (void)n_in; (void)out_size;
  const float* x = (const float*)d_in[0];
  const float* ste = (const float*)d_in[1];
  const float* w_proj = (const float*)d_in[2];
  const float* b_proj = (const float*)d_in[3];
  const float* w_qk = (const float*)d_in[4];
  const float* w_v = (const float*)d_in[5];
  const float* w_out = (const float*)d_in[6];
  const float* b_out = (const float*)d_in[7];
  const float* rotations = (const float*)d_in[8];
  float* out = (float*)d_out;

  // Workspace layout (~216 MB):
  const size_t szh = (size_t)BL * NPAD * DM;         // 17,301,504 elements
  const size_t szst = (size_t)BHTOT * NHASH * NPAD;  // 2,162,688 elements
  const size_t needed = 3 * szh * 4 + 2 * szst * 4;
  if (ws_size < needed) return;  // diagnosable clean failure, not a fault

  float* qk = (float*)d_ws;
  float* v = qk + szh;
  float* att = v + szh;  // also the h buffer (h consumed before att written)
  float* h = att;
  int* st = (int*)(att + szh);
  int* buckets = st + szst;

  h_kernel<<<dim3(NPAD / HTM, BL), dim3(256), 0, stream>>>(
      x, ste, w_proj, b_proj, h);
  qkv_rot_bucket_kernel<<<dim3(NPAD / RTM, BL), dim3(256), 0, stream>>>(
      h, w_qk, w_v, rotations, buckets, qk, v);
  // att aliases h; h fully consumed above — zero it for the atomic accumulate.
  (void)hipMemsetAsync(att, 0, szh * sizeof(float), stream);
  sort_kernel<<<dim3(BHTOT, NHASH), dim3(384), 0, stream>>>(buckets, st);
  attn_fused_kernel<<<dim3(BHTOT), dim3(512), 0, stream>>>(qk, v, st, att);
  outproj_kernel<<<dim3(21, BL), dim3(256), 0, stream>>>(att, w_out, b_out, out);
}